// Round 6
// baseline (58.365 us; speedup 1.0000x reference)
//
#include <hip/hip_runtime.h>
#include <cstddef>

typedef unsigned long long ull;

#define NPIX (1024 * 2048)
#define WW 2048
#define MAXC 200
#define GRIDB 256
#define BLKT 1024
#define PXT 8
#define NW (BLKT / 64)            // 16 waves
#define TAGSH 56
#define DMASK ((1ull << TAGSH) - 1)

union F8 { float4 v[2]; float f[8]; };
union I8 { int4 v[2]; int f[8]; };

__device__ inline ull AL(ull* p) { return __hip_atomic_load(p, __ATOMIC_RELAXED, __HIP_MEMORY_SCOPE_AGENT); }
__device__ inline void AS(ull* p, ull v) { __hip_atomic_store(p, v, __ATOMIC_RELAXED, __HIP_MEMORY_SCOPE_AGENT); }
__device__ inline void ASI(int* p, int v) { __hip_atomic_store(p, v, __ATOMIC_RELAXED, __HIP_MEMORY_SCOPE_AGENT); }
__device__ inline int ALI(int* p) { return __hip_atomic_load(p, __ATOMIC_RELAXED, __HIP_MEMORY_SCOPE_AGENT); }

__device__ inline ull shfl_down_u64(ull v, int o) {
  unsigned lo = (unsigned)v, hi = (unsigned)(v >> 32);
  lo = __shfl_down(lo, o, 64);
  hi = __shfl_down(hi, o, 64);
  return ((ull)hi << 32) | lo;
}
// combined wave reduce: max of k, field-wise sum of z. Lane-0 result.
__device__ inline void wred_kz(ull& k, ull& z) {
  #pragma unroll
  for (int o = 32; o > 0; o >>= 1) {
    ull k2 = shfl_down_u64(k, o), z2 = shfl_down_u64(z, o);
    if (k2 > k) k = k2;
    z += z2;
  }
}
// compile-time-safe 8-way register select (no runtime indexing -> no scratch)
__device__ inline float sel8(const F8& x, int j) {
  const float4 lo = x.v[0], hi = x.v[1];
  float hx = (j & 4) ? hi.x : lo.x, hy = (j & 4) ? hi.y : lo.y;
  float hz = (j & 4) ? hi.z : lo.z, hw = (j & 4) ? hi.w : lo.w;
  float a = (j & 2) ? hz : hx;
  float c = (j & 2) ? hw : hy;
  return (j & 1) ? c : a;
}

__global__ __launch_bounds__(BLKT) void k_all(
    const float* __restrict__ pred,
    ull* __restrict__ slots,        // [GRIDB][8] u64, one 64B line/block:
                                    // [0]=tag|K  [1]=tag|Z  [2..5]=tag|{c0,c1,s0,s1}
    int* __restrict__ prevp, int* __restrict__ nowp,
    int* __restrict__ out)
{
  __shared__ ull lsaK[4], lsaZ[4];
  __shared__ ull lsbK[NW], lsbZ[NW];
  __shared__ int lbad[MAXC];

  const int b = blockIdx.x, tid = threadIdx.x;
  const int wid = tid >> 6, lane = tid & 63;
  const int gtid = b * BLKT + tid;
  const int base = gtid * PXT;
  const float dxs = 2.0f / 2047.0f;   // linspace(0,2,2048) step
  const float dys = 1.0f / 1023.0f;   // linspace(0,1,1024) step

  F8 Av, Bv, Sv, R2, R3;    // spatial_emb x/y, seed score (sign=clustered), raw sigma
  ull iv = 0;               // 8 inst labels (bytes)
  unsigned pp = 0;          // previous iteration's proposal bits

  // ---------------- pre-phase: everything -> registers --------------------
  {
    F8 P, Q;
    const int h = base >> 11, wb = base & (WW - 1);   // 8 | base -> one row
    const float yv = __fmul_rn((float)h, dys);
    P.v[0] = *(const float4*)(pred + base);     P.v[1] = *(const float4*)(pred + base + 4);
    #pragma unroll
    for (int j = 0; j < PXT; j++)
      Av.f[j] = __fadd_rn(tanhf(P.f[j]), __fmul_rn((float)(wb + j), dxs));
    P.v[0] = *(const float4*)(pred + NPIX + base); P.v[1] = *(const float4*)(pred + NPIX + base + 4);
    #pragma unroll
    for (int j = 0; j < PXT; j++)
      Bv.f[j] = __fadd_rn(tanhf(P.f[j]), yv);
    R2.v[0] = *(const float4*)(pred + 2 * NPIX + base); R2.v[1] = *(const float4*)(pred + 2 * NPIX + base + 4);
    R3.v[0] = *(const float4*)(pred + 3 * NPIX + base); R3.v[1] = *(const float4*)(pred + 3 * NPIX + base + 4);
    P.v[0] = *(const float4*)(pred + 5 * NPIX + base); P.v[1] = *(const float4*)(pred + 5 * NPIX + base + 4);
    Q.v[0] = *(const float4*)(pred + 6 * NPIX + base); Q.v[1] = *(const float4*)(pred + 6 * NPIX + base + 4);
    #pragma unroll
    for (int j = 0; j < PXT; j++) {
      float a = P.f[j], bb = Q.f[j];
      float mx = fmaxf(a, bb);
      float ea = expf(__fsub_rn(a, mx));
      float eb = expf(__fsub_rn(bb, mx));
      Sv.f[j] = __fdiv_rn(eb, __fadd_rn(ea, eb));   // softmax(...)[1], bit-exact vs ref
    }
    float bsc = 0.0f; int bj = 0, cnt = 0;
    #pragma unroll
    for (int j = 0; j < PXT; j++) {
      float s = Sv.f[j];
      bool mm = s > 0.5f;
      cnt += mm ? 1 : 0;
      float sc = mm ? s : 0.0f;
      if (sc > bsc) { bsc = sc; bj = j; }
    }
    ull bk = ((ull)__float_as_uint(bsc) << 21) | (ull)(0x1FFFFFu - (unsigned)(base + bj));
    ull bz = ((ull)(unsigned)cnt) << 24;
    wred_kz(bk, bz);
    if (lane == 0) { lsbK[wid] = bk; lsbZ[wid] = bz; }
    if (b == 0)
      for (int c = tid; c < MAXC; c += BLKT) { ASI(&nowp[c], 0); ASI(&prevp[c], 0); }
    __syncthreads();
    ull K = lsbK[0], Z = lsbZ[0];
    #pragma unroll
    for (int i = 1; i < NW; i++) { ull kk = lsbK[i]; if (kk > K) K = kk; Z += lsbZ[i]; }
    const ull tw = 1ull << TAGSH;                   // tag 1
    const int bsidx = 0x1FFFFF - (int)(K & 0x1FFFFF);
    if ((bsidx >> 3) == gtid) {                     // owner thread publishes params
      const int j = bsidx & 7;
      AS(&slots[b * 8 + 2], tw | __float_as_uint(sel8(Av, j)));
      AS(&slots[b * 8 + 3], tw | __float_as_uint(sel8(Bv, j)));
      AS(&slots[b * 8 + 4], tw | __float_as_uint(expf(__fmul_rn(sel8(R2, j), 10.0f))));
      AS(&slots[b * 8 + 5], tw | __float_as_uint(expf(__fmul_rn(sel8(R3, j), 10.0f))));
    }
    if (tid == 0) { AS(&slots[b * 8 + 1], tw | Z); AS(&slots[b * 8 + 0], tw | K); }
  }

  // ---------------- main loop: ONE tagged barrier per iteration -----------
  int count = 1, rem = 0, tstop = 0;
  for (int t = 0; t < (1 << 20); ++t) {
    const unsigned tg = (unsigned)(t + 1) & 0xFFu;
    if (tid < GRIDB) {
      ull* sl = &slots[tid * 8];
      ull k, z;
      for (;;) {
        k = AL(sl); z = AL(sl + 1);
        if (((unsigned)(k >> TAGSH) == tg) & ((unsigned)(z >> TAGSH) == tg)) break;
      }
      k &= DMASK; z &= DMASK;
      wred_kz(k, z);
      if (lane == 0) { lsaK[wid] = k; lsaZ[wid] = z; }
    }
    __syncthreads();                                 // S1
    ull K = lsaK[0], Z = lsaZ[0];
    #pragma unroll
    for (int i = 1; i < 4; i++) { ull kk = lsaK[i]; if (kk > K) K = kk; Z += lsaZ[i]; }
    const int sidx = 0x1FFFFF - (int)(K & 0x1FFFFF);
    const int winb = sidx >> 13;                     // 8192 px per block
    // issue winner-param loads early (overlap with bookkeeping)
    ull* wp = &slots[(ull)winb * 8 + 2];
    ull w2 = AL(wp), w3 = AL(wp + 1), w4 = AL(wp + 2), w5 = AL(wp + 3);

    bool accP = false; int labP = 0;
    if (t == 0) {
      rem = (int)(Z >> 24);                          // initial unclustered count
    } else {
      int ps = (int)((Z >> 24) & 0xFFFFFF), ui = (int)(Z & 0xFFFFFF);
      accP = (ps > 160) &&
             (__fdiv_rn((float)(ui - 1), fmaxf((float)ps, 1.0f)) > 0.5f);
      if (accP) {
        labP = count;
        if (b == 0 && tid == 0) ASI(&prevp[count], ps);
        count++;
      }
      rem -= ui;                                     // flips incl. seed
    }
    if (accP && pp) {                                // deferred labeling of t-1
      #pragma unroll
      for (int j = 0; j < PXT; j++)
        if ((pp >> j) & 1) iv = (iv & ~(0xFFull << (8 * j))) | ((ull)(unsigned)labP << (8 * j));
    }
    if (!((rem > 160) && (count < MAXC))) { tstop = t; break; }
    const float score = __uint_as_float((unsigned)((K >> 21) & 0x7FFFFFFF));
    if (score < 0.5f) { tstop = t; break; }

    // winner params: tagged slot words (L3-hot); bounded spin + exact fallback
    float c0, c1, s0, s1;
    {
      bool ok; int spins = 0;
      for (;;) {
        ok = ((unsigned)(w2 >> TAGSH) == tg) & ((unsigned)(w3 >> TAGSH) == tg) &
             ((unsigned)(w4 >> TAGSH) == tg) & ((unsigned)(w5 >> TAGSH) == tg);
        if (ok || ++spins >= 512) break;
        w2 = AL(wp); w3 = AL(wp + 1); w4 = AL(wp + 2); w5 = AL(wp + 3);
      }
      if (ok) {
        c0 = __uint_as_float((unsigned)w2); c1 = __uint_as_float((unsigned)w3);
        s0 = __uint_as_float((unsigned)w4); s1 = __uint_as_float((unsigned)w5);
      } else {                                       // bit-identical recompute
        const float p0 = pred[sidx], p1 = pred[NPIX + sidx];
        const float p2 = pred[2 * NPIX + sidx], p3 = pred[3 * NPIX + sidx];
        c0 = __fadd_rn(tanhf(p0), __fmul_rn((float)(sidx & (WW - 1)), dxs));
        c1 = __fadd_rn(tanhf(p1), __fmul_rn((float)(sidx >> 11), dys));
        s0 = expf(__fmul_rn(p2, 10.0f));
        s1 = expf(__fmul_rn(p3, 10.0f));
      }
    }

    // register-only sweep (expf only within 5.5e-5 window of the threshold)
    float bsc = 0.0f; int bj = 0, psl = 0, uil = 0; unsigned ppn = 0;
    #pragma unroll
    for (int j = 0; j < PXT; j++) {
      float s = Sv.f[j];
      float d0 = __fsub_rn(Av.f[j], c0);
      float d1 = __fsub_rn(Bv.f[j], c1);
      float tt = __fadd_rn(__fmul_rn(__fmul_rn(d0, d0), s0),
                           __fmul_rn(__fmul_rn(d1, d1), s1));
      bool dok = (tt <= 0.693120f);                  // exp(-t) surely > 0.5
      if (__builtin_expect((!dok) && (tt < 0.693175f), 0))
        dok = (expf(-tt) > 0.5f);                    // boundary: exact OCML expf
      bool pr = dok && (fabsf(s) > 0.5f);
      if (pr) {
        ppn |= 1u << j;
        psl++;
        if (s > 0.5f) { uil++; s = -s; Sv.f[j] = s; }
      }
      float sc = (s > 0.5f) ? s : 0.0f;
      if (sc > bsc) { bsc = sc; bj = j; }
    }
    pp = ppn;
    ull bk = ((ull)__float_as_uint(bsc) << 21) | (ull)(0x1FFFFFu - (unsigned)(base + bj));
    ull bz = ((ull)(unsigned)psl << 24) | (unsigned)uil;
    wred_kz(bk, bz);
    if (lane == 0) { lsbK[wid] = bk; lsbZ[wid] = bz; }
    __syncthreads();                                 // S2
    {
      ull K2 = lsbK[0], Z2 = lsbZ[0];
      #pragma unroll
      for (int i = 1; i < NW; i++) { ull kk = lsbK[i]; if (kk > K2) K2 = kk; Z2 += lsbZ[i]; }
      const ull tw = ((ull)((unsigned)(t + 2) & 0xFFu)) << TAGSH;
      const int bsidx = 0x1FFFFF - (int)(K2 & 0x1FFFFF);
      if ((bsidx >> 3) == gtid) {                    // owner publishes params
        const int j = bsidx & 7;
        AS(&slots[b * 8 + 2], tw | __float_as_uint(sel8(Av, j)));
        AS(&slots[b * 8 + 3], tw | __float_as_uint(sel8(Bv, j)));
        AS(&slots[b * 8 + 4], tw | __float_as_uint(expf(__fmul_rn(sel8(R2, j), 10.0f))));
        AS(&slots[b * 8 + 5], tw | __float_as_uint(expf(__fmul_rn(sel8(R3, j), 10.0f))));
      }
      if (tid == 0) { AS(&slots[b * 8 + 1], tw | Z2); AS(&slots[b * 8 + 0], tw | K2); }
    }
  }

  // ---------------- epilogue: bincount(skip 0) -> barrier -> bad -> out ---
  for (int c = tid; c < MAXC; c += BLKT) lbad[c] = 0;
  __syncthreads();
  {
    int cur = -1, acc = 0;
    #pragma unroll
    for (int j = 0; j < PXT; j++) {
      int lb = (int)((iv >> (8 * j)) & 0xFF);
      if (lb == cur) acc++;
      else { if (cur > 0) atomicAdd(&lbad[cur], acc); cur = lb; acc = 1; }
    }
    if (cur > 0) atomicAdd(&lbad[cur], acc);
  }
  __syncthreads();
  for (int c = tid + 1; c < MAXC; c += BLKT)
    if (lbad[c]) atomicAdd(&nowp[c], lbad[c]);
  __syncthreads();                                   // block's atomics issued
  {
    const unsigned etg = (unsigned)(tstop + 2) & 0xFFu;
    if (tid == 0)
      __hip_atomic_store(&slots[b * 8], ((ull)etg) << TAGSH,
                         __ATOMIC_RELEASE, __HIP_MEMORY_SCOPE_AGENT);
    if (tid < GRIDB) {
      ull* sl = &slots[tid * 8];
      while ((unsigned)(__hip_atomic_load(sl, __ATOMIC_ACQUIRE,
                                          __HIP_MEMORY_SCOPE_AGENT) >> TAGSH) != etg) {}
    }
  }
  __syncthreads();
  if (tid < MAXC) {
    int c = tid;
    int nw = (c == 0) ? 0 : ALI(&nowp[c]);
    int pv = ALI(&prevp[c]);
    float ratio = __fdiv_rn((float)nw, (float)(pv > 1 ? pv : 1));
    int bd = (nw != pv) && (nw > 0) && ((nw < 3 * 160) || (ratio < 0.5f));
    if (c == 0) bd = 0;
    lbad[c] = bd;
  }
  __syncthreads();
  {
    I8 O;
    #pragma unroll
    for (int j = 0; j < PXT; j++) {
      int v = (int)((iv >> (8 * j)) & 0xFF);
      O.f[j] = lbad[v] ? 0 : v;
    }
    *(int4*)(out + base) = O.v[0];
    *(int4*)(out + base + 4) = O.v[1];
  }
}

extern "C" void kernel_launch(void* const* d_in, const int* in_sizes, int n_in,
                              void* d_out, int out_size, void* d_ws, size_t ws_size,
                              hipStream_t stream) {
  const float* pred = (const float*)d_in[0];
  char* ws = (char*)d_ws;
  size_t off = 0;
  ull* slots = (ull*)(ws + off); off += (size_t)GRIDB * 8 * sizeof(ull);
  int* prevp = (int*)(ws + off); off += MAXC * sizeof(int);
  int* nowp  = (int*)(ws + off); off += MAXC * sizeof(int);
  int* out = (int*)d_out;

  hipLaunchKernelGGL(k_all, dim3(GRIDB), dim3(BLKT), 0, stream,
                     pred, slots, prevp, nowp, out);
}